// Round 17
// baseline (110.712 us; speedup 1.0000x reference)
//
#include <hip/hip_runtime.h>
#include <hip/hip_bf16.h>
#include <math.h>

#define HWX 16384   // 128*128 pixels per (b, channel) plane

typedef __attribute__((ext_vector_type(8))) short short8v;
typedef __attribute__((ext_vector_type(4))) float f32x4;

__device__ inline ushort f2bf(float x) {
    union { __hip_bfloat16 h; ushort u; } cv;
    cv.h = __float2bfloat16(x);
    return cv.u;
}

// ---------------------------------------------------------------------------
// Pack six 5x5-conv weight sets -> Wpk[oc][k] bf16, k = (ky*5+kx)*64 + ic.
// ---------------------------------------------------------------------------
__global__ __launch_bounds__(256) void packw_kernel(
    const float* __restrict__ w1, const float* __restrict__ b1,
    const float* __restrict__ w2, const float* __restrict__ b2,
    const float* __restrict__ w4, const float* __restrict__ b4,
    const float* __restrict__ w5, const float* __restrict__ b5,
    const float* __restrict__ wz, const float* __restrict__ bz,
    const float* __restrict__ wm, const float* __restrict__ bm,
    __hip_bfloat16* __restrict__ Wpk, float* __restrict__ bpack)
{
    const int idx = blockIdx.x * 256 + threadIdx.x;
    if (idx < 96) {
        const int o = idx; float v = 0.f;
        if      (o < 18) v = b1[o];
        else if (o < 36) v = b2[o - 18];
        else if (o < 54) v = b4[o - 36];
        else if (o < 72) v = b5[o - 54];
        else if (o < 81) v = bz[o - 72];
        else if (o < 90) v = bm[o - 81];
        bpack[o] = v;
    }
    if (idx < 96 * 1600) {
        const int o   = idx / 1600;
        const int k   = idx - o * 1600;
        const int kyx = k >> 6;
        const int ic  = k & 63;
        const int off = ic * 25 + kyx;
        float v = 0.f;
        if      (o < 18) v = w1[o * 1600 + off];
        else if (o < 36) v = w2[(o - 18) * 1600 + off];
        else if (o < 54) v = w4[(o - 36) * 1600 + off];
        else if (o < 72) v = w5[(o - 54) * 1600 + off];
        else if (o < 81) v = wz[(o - 72) * 1600 + off];
        else if (o < 90) v = wm[(o - 81) * 1600 + off];
        Wpk[idx] = __float2bfloat16(v);
    }
}

// ---------------------------------------------------------------------------
// offset_source -> channel-last bf16 with baked-in zero pad ring.
// ---------------------------------------------------------------------------
__global__ __launch_bounds__(256) void packosT_kernel(
    const float* __restrict__ src, __hip_bfloat16* __restrict__ osT)
{
    const int yy = blockIdx.x;
    const int b  = blockIdx.y;
    __hip_bfloat16* dst = osT + ((size_t)b * 132 + yy) * 132 * 64;
    for (int idx = threadIdx.x; idx < 132 * 64; idx += 256) {
        const int xx = idx >> 6;
        const int c  = idx & 63;
        float v = 0.f;
        if (yy >= 2 && yy < 130 && xx >= 2 && xx < 130)
            v = src[(((b << 6) + c) << 14) + ((yy - 2) << 7) + (xx - 2)];
        dst[idx] = __float2bfloat16(v);
    }
}

// ---------------------------------------------------------------------------
// MFMA conv, 2-phase LDS-staged GEMM (validated r11).
// ---------------------------------------------------------------------------
__global__ __launch_bounds__(256) void conv_mfma_kernel(
    const __hip_bfloat16* __restrict__ Wpk,
    const float* __restrict__ bpack,
    const __hip_bfloat16* __restrict__ osT,
    float* __restrict__ offs, float* __restrict__ zbuf, float* __restrict__ mbuf)
{
    __shared__ __align__(16) ushort slab[5 * 68 * 64];
    __shared__ __align__(16) ushort wbuf[2][96 * 64];

    const int bx = blockIdx.x;
    const int y  = bx >> 1;
    const int x0 = (bx & 1) << 6;
    const int b  = blockIdx.y;
    const int t    = threadIdx.x;
    const int wv   = t >> 6;
    const int lane = t & 63;
    const int l15  = lane & 15;
    const int kgrp = lane >> 4;
    const int wm   = wv >> 1;
    const int wn   = wv & 1;

    const ushort* ob = (const ushort*)osT + (size_t)b * (132 * 132 * 64);
    const ushort* Wg = (const ushort*)Wpk;

    for (int c = t; c < 2720; c += 256) {
        const int r5  = c / 544;
        const int rem = c - r5 * 544;
        const int col = rem >> 3;
        const int cb  = rem & 7;
        const short8v v = *(const short8v*)(ob + (((y + r5) * 132 + x0 + col) << 6) + (cb << 3));
        const int slot = r5 * 544 + (col << 3) + (cb ^ (col & 7));
        *(short8v*)((char*)slab + slot * 16) = v;
    }

#define STAGE_W(kyx, bi)                                                       \
    _Pragma("unroll")                                                          \
    for (int it = 0; it < 3; ++it) {                                           \
        const int c  = it * 256 + t;                                           \
        const int oc = c >> 3, cb = c & 7;                                     \
        const ushort* src = Wg + oc * 1600 + (kyx) * 64 + ((cb ^ (oc & 7)) << 3); \
        __builtin_amdgcn_global_load_lds(                                      \
            (const __attribute__((address_space(1))) void*)src,                \
            (__attribute__((address_space(3))) void*)((char*)wbuf[bi] + (it * 256 + wv * 64) * 16), \
            16, 0, 0);                                                         \
    }

    STAGE_W(0, 0)
    __syncthreads();

    f32x4 acc[3][2];
    #pragma unroll
    for (int m = 0; m < 3; ++m)
        #pragma unroll
        for (int n = 0; n < 2; ++n) acc[m][n] = (f32x4){0.f, 0.f, 0.f, 0.f};

    for (int kyx = 0; kyx < 25; ++kyx) {
        const int bi = kyx & 1;
        if (kyx < 24) STAGE_W(kyx + 1, bi ^ 1)
        const int ky = kyx / 5, kx = kyx % 5;
        #pragma unroll
        for (int kc = 0; kc < 2; ++kc) {
            const int kcg = (kc << 2) + kgrp;
            short8v af[3], bf[2];
            #pragma unroll
            for (int m = 0; m < 3; ++m) {
                const int oc = wm * 48 + m * 16 + l15;
                af[m] = *(const short8v*)((char*)wbuf[bi] + ((oc << 3) + (kcg ^ (oc & 7))) * 16);
            }
            #pragma unroll
            for (int n = 0; n < 2; ++n) {
                const int col = wn * 32 + n * 16 + l15 + kx;
                bf[n] = *(const short8v*)((char*)slab + ((ky * 68 + col) * 8 + (kcg ^ (col & 7))) * 16);
            }
            #pragma unroll
            for (int m = 0; m < 3; ++m)
                #pragma unroll
                for (int n = 0; n < 2; ++n)
                    acc[m][n] = __builtin_amdgcn_mfma_f32_16x16x32_bf16(af[m], bf[n], acc[m][n], 0, 0, 0);
        }
        __syncthreads();
    }
#undef STAGE_W

    #pragma unroll
    for (int m = 0; m < 3; ++m) {
        const int ocb = wm * 48 + m * 16 + (kgrp << 2);
        #pragma unroll
        for (int n = 0; n < 2; ++n) {
            const int x = x0 + wn * 32 + n * 16 + l15;
            const int p = (y << 7) + x;
            #pragma unroll
            for (int r = 0; r < 4; ++r) {
                const int o = ocb + r;
                const float v = acc[m][n][r] + bpack[o];
                if (o < 72) {
                    const int i = o / 18, ch = o - i * 18;
                    offs[i * (2 * 18 * HWX) + (((b * 18) + ch) << 14) + p] = v;
                } else if (o < 81) {
                    zbuf[((b * 9 + (o - 72)) << 14) + p] = 3.f / (1.f + expf(-v));
                } else if (o < 90) {
                    mbuf[((b * 9 + (o - 81)) << 14) + p] = 1.f / (1.f + expf(-v));
                }
            }
        }
    }
}

// ---------------------------------------------------------------------------
// Transpose img fp32 -> imgT bf16 channel-last.
// ---------------------------------------------------------------------------
__global__ __launch_bounds__(256) void transpose_kernel(
    const float* __restrict__ i0, const float* __restrict__ i1,
    const float* __restrict__ i2, const float* __restrict__ i3,
    ushort* __restrict__ imgT)
{
    const int img = blockIdx.z;
    const int b   = blockIdx.y;
    const int p0  = blockIdx.x << 6;
    const float* src = (img == 0) ? i0 : (img == 1) ? i1 : (img == 2) ? i2 : i3;

    __shared__ float tile[64][65];
    const int t = threadIdx.x;
    const int pp = t & 63, c0 = t >> 6;
    #pragma unroll
    for (int k = 0; k < 16; ++k) {
        const int c = (k << 2) + c0;
        tile[c][pp] = src[(((b << 6) + c) << 14) + p0 + pp];
    }
    __syncthreads();
    const int c2 = t & 31, pl = t >> 5;
    #pragma unroll
    for (int k = 0; k < 8; ++k) {
        const int pi = (k << 3) + pl;
        const uint packed = (uint)f2bf(tile[2 * c2][pi])
                          | ((uint)f2bf(tile[2 * c2 + 1][pi]) << 16);
        *(uint*)(imgT + ((size_t)(((img << 1) + b) << 14) + p0 + pi) * 64 + 2 * c2)
            = packed;
    }
}

// ---------------------------------------------------------------------------
// WcPk[oc][cn'] bf16 with n-major K-order: cn' = n*64 + c  <-  wc[o][c][n].
// ---------------------------------------------------------------------------
__global__ __launch_bounds__(256) void wcpk_kernel(
    const float* __restrict__ wc, __hip_bfloat16* __restrict__ WcPk)
{
    const int idx = blockIdx.x * 256 + threadIdx.x;
    if (idx < 36864) {
        const int oc  = idx / 576;
        const int cnp = idx - oc * 576;
        const int n   = cnp >> 6;
        const int c   = cnp & 63;
        WcPk[idx] = __float2bfloat16(wc[oc * 576 + c * 9 + n]);
    }
}

// ---------------------------------------------------------------------------
// Fused deform-sample + MFMA contraction — QUAD-TAP variant (r17).
// r16 confirmed gather time ∝ per-wave load-instruction count. Halve again:
// block = 512 threads (8 waves), 16 px; lane = (c8, tap 0..3, pxs 0..1);
// ONE uint4 load per (n,i) per lane (its tap) -> 36 loads/thread (was 72).
// Tap partials combined via shfl_xor(8) + shfl_xor(16) (lane bits 3-4 =
// tap); tap==0 lanes write the b128 finalize. 4 blocks/CU x 8 waves =
// 32 waves/CU (100% thread-bound occupancy). Phase C on waves 0-3 only.
// ---------------------------------------------------------------------------
__global__ __launch_bounds__(512) void fused_kernel(
    const float* __restrict__ offs,   // [4][2][18][HWX]
    const float* __restrict__ zbuf,   // [2][9][HWX]
    const float* __restrict__ mbuf,   // [2][9][HWX]
    const ushort* __restrict__ imgT,  // [4][2][HWX][64] bf16
    const __hip_bfloat16* __restrict__ WcPk,  // [64][576] n-major
    float* __restrict__ out)          // [2][64][HWX]
{
    __shared__ __hip_bfloat16 s_sb[16 * 584];   // 18688 B
    __shared__ uint4 s_tap[16 * 36];            // 9216 B  => 27904 B

    const int t   = threadIdx.x;
    const int pid = blockIdx.x;
    const int b   = pid >> 10;
    const int rem = pid & 1023;
    const int h   = rem >> 3;
    const int w0p = (rem & 7) << 4;

    // ---- phase A: taps -> packed uint4 ----
    for (int u = t; u < 576; u += 512) {
        const int px_  = u / 36;
        const int unit = u - px_ * 36;
        const int i    = unit / 9;
        const int n    = unit - i * 9;
        const int wcol = w0p + px_;
        const int p    = (h << 7) + wcol;

        const float* ob = offs + i * (2 * 18 * HWX) + ((b * 18) << 14);
        const float ox = ob[(n << 14) + p];
        const float oy = ob[((n + 9) << 14) + p];
        const float z  = zbuf[((b * 9 + n) << 14) + p];
        const float mm = mbuf[((b * 9 + n) << 14) + p];

        const float zc0 = (i == 0) ? 1.f : 0.f;
        const float zc1 = (i == 0) ? (-11.f / 6.f) : (i == 1) ? 3.f
                         : (i == 2) ? -1.5f : (1.f / 3.f);
        const float zc2 = (i == 0) ? 1.f : (i == 1) ? -2.5f
                         : (i == 2) ? 2.f : -0.5f;
        const float zc3 = (i == 0) ? (-1.f / 6.f) : (i == 1) ? 0.5f
                         : (i == 2) ? -0.5f : (1.f / 6.f);
        const float zw   = zc0 + z * (zc1 + z * (zc2 + z * zc3));
        const float coef = zw * mm;

        const float pxf = (float)(h + n / 3) + ox;
        const float pyf = (float)(wcol + n % 3) + oy;
        const float flx = floorf(pxf), fly = floorf(pyf);
        const float qltx = fminf(fmaxf(flx, 0.f), 129.f);
        const float qrbx = fminf(fmaxf(flx + 1.f, 0.f), 129.f);
        const float qlty = fminf(fmaxf(fly, 0.f), 129.f);
        const float qrby = fminf(fmaxf(fly + 1.f, 0.f), 129.f);
        const float pxc = fminf(fmaxf(pxf, 0.f), 129.f);
        const float pyc = fminf(fmaxf(pyf, 0.f), 129.f);
        const float gxl = 1.f + (qltx - pxc);
        const float gxr = 1.f - (qrbx - pxc);
        const float gyl = 1.f + (qlty - pyc);
        const float gyr = 1.f - (qrby - pyc);
        const int ixl = (int)qltx, ixr = (int)qrbx;
        const int iyl = (int)qlty, iyr = (int)qrby;

        uint i0_, i1_, i2_, i3_, u0_, u1_, u2_, u3_;
        auto mk = [&](int qx, int qy, float g, uint& ii, uint& ww) {
            const bool valid = (qx >= 1) && (qx <= 128) && (qy >= 1) && (qy <= 128);
            ii = valid ? (uint)(((qx - 1) << 7) + (qy - 1)) : 0u;
            ww = valid ? (uint)f2bf(g * coef) : 0u;
        };
        mk(ixl, iyl, gxl * gyl, i0_, u0_);
        mk(ixr, iyr, gxr * gyr, i1_, u1_);
        mk(ixr, iyl, gxr * gyl, i2_, u2_);
        mk(ixl, iyr, gxl * gyr, i3_, u3_);
        uint4 tp;
        tp.x = i0_ | (i1_ << 16);
        tp.y = i2_ | (i3_ << 16);
        tp.z = u0_ | (u1_ << 16);
        tp.w = u2_ | (u3_ << 16);
        s_tap[u] = tp;
    }
    __syncthreads();

    // ---- phase B: one tap per lane ----
    const int lane = t & 63;
    const int wv   = t >> 6;            // 0..7
    const int c8   = lane & 7;
    const int tap  = (lane >> 3) & 3;
    const int pxs  = lane >> 5;         // 0..1
    const int px   = (wv << 1) + pxs;   // 0..15
    const int tb   = px * 36;
    const int cByte = c8 << 4;          // 8 channels * 2B

    #pragma unroll 1
    for (int n = 0; n < 9; ++n) {
        float s8[8];
        #pragma unroll
        for (int m = 0; m < 8; ++m) s8[m] = 0.f;

        #pragma unroll
        for (int i = 0; i < 4; ++i) {
            const uint4 tp = s_tap[tb + i * 9 + n];
            const uint pair = (tap & 2) ? tp.y : tp.x;
            const uint wpr  = (tap & 2) ? tp.w : tp.z;
            const uint pidx = (tap & 1) ? (pair >> 16) : (pair & 0xffffu);
            const float wT  = __uint_as_float((tap & 1) ? (wpr & 0xffff0000u)
                                                        : (wpr << 16));
            const char* ibl = (const char*)imgT + (((size_t)((i << 1) + b)) << 21) + cByte;
            const uint4 v = *(const uint4*)(ibl + (pidx << 7));
            s8[0] = fmaf(wT, __uint_as_float(v.x << 16),         s8[0]);
            s8[1] = fmaf(wT, __uint_as_float(v.x & 0xffff0000u), s8[1]);
            s8[2] = fmaf(wT, __uint_as_float(v.y << 16),         s8[2]);
            s8[3] = fmaf(wT, __uint_as_float(v.y & 0xffff0000u), s8[3]);
            s8[4] = fmaf(wT, __uint_as_float(v.z << 16),         s8[4]);
            s8[5] = fmaf(wT, __uint_as_float(v.z & 0xffff0000u), s8[5]);
            s8[6] = fmaf(wT, __uint_as_float(v.w << 16),         s8[6]);
            s8[7] = fmaf(wT, __uint_as_float(v.w & 0xffff0000u), s8[7]);
        }

        // combine the 4 tap partials: lane bits 3-4 index the tap
        #pragma unroll
        for (int m = 0; m < 8; ++m) {
            s8[m] += __shfl_xor(s8[m], 8);
            s8[m] += __shfl_xor(s8[m], 16);
        }

        if (tap == 0) {
            uint4 pk;
            pk.x = (uint)f2bf(s8[0]) | ((uint)f2bf(s8[1]) << 16);
            pk.y = (uint)f2bf(s8[2]) | ((uint)f2bf(s8[3]) << 16);
            pk.z = (uint)f2bf(s8[4]) | ((uint)f2bf(s8[5]) << 16);
            pk.w = (uint)f2bf(s8[6]) | ((uint)f2bf(s8[7]) << 16);
            *(uint4*)((char*)s_sb + px * 1168 + n * 128 + cByte) = pk;
        }
    }
    __syncthreads();

    // ---- phase C: MFMA contraction (waves 0-3; 16 oc each) ----
    if (wv < 4) {
        const int l15  = lane & 15;
        const int kgrp = lane >> 4;
        const ushort* Wb = (const ushort*)WcPk + (wv * 16 + l15) * 576 + kgrp * 8;
        const ushort* sb = (const ushort*)s_sb + l15 * 584 + kgrp * 8;

        f32x4 acc = {0.f, 0.f, 0.f, 0.f};
        #pragma unroll
        for (int ks = 0; ks < 18; ++ks) {
            const short8v a  = *(const short8v*)(Wb + ks * 32);
            const short8v bb = *(const short8v*)(sb + ks * 32);
            acc = __builtin_amdgcn_mfma_f32_16x16x32_bf16(a, bb, acc, 0, 0, 0);
        }

        const int p = (h << 7) + w0p + l15;
        #pragma unroll
        for (int r = 0; r < 4; ++r) {
            const int oc = wv * 16 + (kgrp << 2) + r;
            out[(((b << 6) + oc) << 14) + p] = acc[r];
        }
    }
}

// ---------------------------------------------------------------------------
extern "C" void kernel_launch(void* const* d_in, const int* in_sizes, int n_in,
                              void* d_out, int out_size, void* d_ws, size_t ws_size,
                              hipStream_t stream) {
    (void)in_sizes; (void)n_in; (void)out_size; (void)ws_size;
    const float* img1  = (const float*)d_in[0];
    const float* img2  = (const float*)d_in[1];
    const float* img4  = (const float*)d_in[2];
    const float* img5  = (const float*)d_in[3];
    const float* osrc  = (const float*)d_in[4];
    const float* w_pc1 = (const float*)d_in[5];
    const float* b_pc1 = (const float*)d_in[6];
    const float* w_pc2 = (const float*)d_in[7];
    const float* b_pc2 = (const float*)d_in[8];
    const float* w_pc4 = (const float*)d_in[9];
    const float* b_pc4 = (const float*)d_in[10];
    const float* w_pc5 = (const float*)d_in[11];
    const float* b_pc5 = (const float*)d_in[12];
    const float* w_z   = (const float*)d_in[13];
    const float* b_z   = (const float*)d_in[14];
    const float* w_m   = (const float*)d_in[15];
    const float* b_m   = (const float*)d_in[16];
    const float* w_cv  = (const float*)d_in[17];
    float* out = (float*)d_out;

    float* wsf  = (float*)d_ws;
    float* offs = wsf;                    // 4 * 589824 floats
    float* zbuf = wsf + 4 * 589824;       // 294912
    float* mbuf = zbuf + 294912;          // 294912
    float* WcTr = mbuf + 294912;          // 36864-float region
    float* imgTr = WcTr + 36864;          // 8388608-float region

    __hip_bfloat16* WcPk  = (__hip_bfloat16*)WcTr;
    ushort*         imgTb = (ushort*)imgTr;

    // Wpk/bpack/osT ALIAS the imgT region (conv pipeline finishes before
    // transpose_kernel overwrites imgT — same-stream serialization).
    __hip_bfloat16* Wpk   = (__hip_bfloat16*)imgTr;            // 153600 bf16
    float*          bpack = imgTr + 76800;                     // 96 f32
    __hip_bfloat16* osT   = (__hip_bfloat16*)(imgTr + 76912);  // 2230272 bf16

    packw_kernel<<<dim3((96 * 1600 + 255) / 256), 256, 0, stream>>>(
        w_pc1, b_pc1, w_pc2, b_pc2, w_pc4, b_pc4, w_pc5, b_pc5,
        w_z, b_z, w_m, b_m, Wpk, bpack);
    packosT_kernel<<<dim3(132, 2), 256, 0, stream>>>(osrc, osT);
    conv_mfma_kernel<<<dim3(256, 2), 256, 0, stream>>>(
        Wpk, bpack, osT, offs, zbuf, mbuf);
    transpose_kernel<<<dim3(256, 2, 4), 256, 0, stream>>>(img1, img2, img4, img5, imgTb);
    wcpk_kernel<<<dim3(144), 256, 0, stream>>>(w_cv, WcPk);
    fused_kernel<<<dim3(2048), 512, 0, stream>>>(offs, zbuf, mbuf, imgTb, WcPk, out);
}

// Round 18
// 98.445 us; speedup vs baseline: 1.1246x; 1.1246x over previous
//
#include <hip/hip_runtime.h>
#include <hip/hip_bf16.h>
#include <math.h>

#define HWX 16384   // 128*128 pixels per (b, channel) plane

typedef __attribute__((ext_vector_type(8))) short short8v;
typedef __attribute__((ext_vector_type(4))) float f32x4;

__device__ inline ushort f2bf(float x) {
    union { __hip_bfloat16 h; ushort u; } cv;
    cv.h = __float2bfloat16(x);
    return cv.u;
}

// ---------------------------------------------------------------------------
// Combined prep: [0,600) packw | [600,864) packosT | [864,1008) wcpk
//   packw:  Wpk[oc][k] bf16, k=(ky*5+kx)*64+ic; bias fp32 bpack[96].
//   packosT: osT[b][132][132][64] bf16 with zero pad ring.
//   wcpk:   WcPk[oc][cn'] bf16, cn' = n*64+c (n-major K).
// ---------------------------------------------------------------------------
__global__ __launch_bounds__(256) void prep_kernel(
    const float* __restrict__ w1, const float* __restrict__ b1,
    const float* __restrict__ w2, const float* __restrict__ b2,
    const float* __restrict__ w4, const float* __restrict__ b4,
    const float* __restrict__ w5, const float* __restrict__ b5,
    const float* __restrict__ wz, const float* __restrict__ bz,
    const float* __restrict__ wm, const float* __restrict__ bm,
    const float* __restrict__ osrc, const float* __restrict__ wc,
    __hip_bfloat16* __restrict__ Wpk, float* __restrict__ bpack,
    __hip_bfloat16* __restrict__ osT, __hip_bfloat16* __restrict__ WcPk)
{
    const int bid = blockIdx.x;
    if (bid < 600) {
        const int idx = bid * 256 + threadIdx.x;
        if (idx < 96) {
            const int o = idx; float v = 0.f;
            if      (o < 18) v = b1[o];
            else if (o < 36) v = b2[o - 18];
            else if (o < 54) v = b4[o - 36];
            else if (o < 72) v = b5[o - 54];
            else if (o < 81) v = bz[o - 72];
            else if (o < 90) v = bm[o - 81];
            bpack[o] = v;
        }
        if (idx < 96 * 1600) {
            const int o   = idx / 1600;
            const int k   = idx - o * 1600;
            const int kyx = k >> 6;
            const int ic  = k & 63;
            const int off = ic * 25 + kyx;
            float v = 0.f;
            if      (o < 18) v = w1[o * 1600 + off];
            else if (o < 36) v = w2[(o - 18) * 1600 + off];
            else if (o < 54) v = w4[(o - 36) * 1600 + off];
            else if (o < 72) v = w5[(o - 54) * 1600 + off];
            else if (o < 81) v = wz[(o - 72) * 1600 + off];
            else if (o < 90) v = wm[(o - 81) * 1600 + off];
            Wpk[idx] = __float2bfloat16(v);
        }
    } else if (bid < 864) {
        const int blk = bid - 600;
        const int yy = blk % 132;
        const int b  = blk / 132;
        __hip_bfloat16* dst = osT + ((size_t)b * 132 + yy) * 132 * 64;
        for (int idx = threadIdx.x; idx < 132 * 64; idx += 256) {
            const int xx = idx >> 6;
            const int c  = idx & 63;
            float v = 0.f;
            if (yy >= 2 && yy < 130 && xx >= 2 && xx < 130)
                v = osrc[(((b << 6) + c) << 14) + ((yy - 2) << 7) + (xx - 2)];
            dst[idx] = __float2bfloat16(v);
        }
    } else {
        const int idx = (bid - 864) * 256 + threadIdx.x;
        if (idx < 36864) {
            const int oc  = idx / 576;
            const int cnp = idx - oc * 576;
            const int n   = cnp >> 6;
            const int c   = cnp & 63;
            WcPk[idx] = __float2bfloat16(wc[oc * 576 + c * 9 + n]);
        }
    }
}

// ---------------------------------------------------------------------------
// MFMA conv, 2-phase LDS-staged GEMM (validated r11).
// ---------------------------------------------------------------------------
__global__ __launch_bounds__(256) void conv_mfma_kernel(
    const __hip_bfloat16* __restrict__ Wpk,
    const float* __restrict__ bpack,
    const __hip_bfloat16* __restrict__ osT,
    float* __restrict__ offs, float* __restrict__ zbuf, float* __restrict__ mbuf)
{
    __shared__ __align__(16) ushort slab[5 * 68 * 64];
    __shared__ __align__(16) ushort wbuf[2][96 * 64];

    const int bx = blockIdx.x;
    const int y  = bx >> 1;
    const int x0 = (bx & 1) << 6;
    const int b  = blockIdx.y;
    const int t    = threadIdx.x;
    const int wv   = t >> 6;
    const int lane = t & 63;
    const int l15  = lane & 15;
    const int kgrp = lane >> 4;
    const int wm   = wv >> 1;
    const int wn   = wv & 1;

    const ushort* ob = (const ushort*)osT + (size_t)b * (132 * 132 * 64);
    const ushort* Wg = (const ushort*)Wpk;

    for (int c = t; c < 2720; c += 256) {
        const int r5  = c / 544;
        const int rem = c - r5 * 544;
        const int col = rem >> 3;
        const int cb  = rem & 7;
        const short8v v = *(const short8v*)(ob + (((y + r5) * 132 + x0 + col) << 6) + (cb << 3));
        const int slot = r5 * 544 + (col << 3) + (cb ^ (col & 7));
        *(short8v*)((char*)slab + slot * 16) = v;
    }

#define STAGE_W(kyx, bi)                                                       \
    _Pragma("unroll")                                                          \
    for (int it = 0; it < 3; ++it) {                                           \
        const int c  = it * 256 + t;                                           \
        const int oc = c >> 3, cb = c & 7;                                     \
        const ushort* src = Wg + oc * 1600 + (kyx) * 64 + ((cb ^ (oc & 7)) << 3); \
        __builtin_amdgcn_global_load_lds(                                      \
            (const __attribute__((address_space(1))) void*)src,                \
            (__attribute__((address_space(3))) void*)((char*)wbuf[bi] + (it * 256 + wv * 64) * 16), \
            16, 0, 0);                                                         \
    }

    STAGE_W(0, 0)
    __syncthreads();

    f32x4 acc[3][2];
    #pragma unroll
    for (int m = 0; m < 3; ++m)
        #pragma unroll
        for (int n = 0; n < 2; ++n) acc[m][n] = (f32x4){0.f, 0.f, 0.f, 0.f};

    for (int kyx = 0; kyx < 25; ++kyx) {
        const int bi = kyx & 1;
        if (kyx < 24) STAGE_W(kyx + 1, bi ^ 1)
        const int ky = kyx / 5, kx = kyx % 5;
        #pragma unroll
        for (int kc = 0; kc < 2; ++kc) {
            const int kcg = (kc << 2) + kgrp;
            short8v af[3], bf[2];
            #pragma unroll
            for (int m = 0; m < 3; ++m) {
                const int oc = wm * 48 + m * 16 + l15;
                af[m] = *(const short8v*)((char*)wbuf[bi] + ((oc << 3) + (kcg ^ (oc & 7))) * 16);
            }
            #pragma unroll
            for (int n = 0; n < 2; ++n) {
                const int col = wn * 32 + n * 16 + l15 + kx;
                bf[n] = *(const short8v*)((char*)slab + ((ky * 68 + col) * 8 + (kcg ^ (col & 7))) * 16);
            }
            #pragma unroll
            for (int m = 0; m < 3; ++m)
                #pragma unroll
                for (int n = 0; n < 2; ++n)
                    acc[m][n] = __builtin_amdgcn_mfma_f32_16x16x32_bf16(af[m], bf[n], acc[m][n], 0, 0, 0);
        }
        __syncthreads();
    }
#undef STAGE_W

    #pragma unroll
    for (int m = 0; m < 3; ++m) {
        const int ocb = wm * 48 + m * 16 + (kgrp << 2);
        #pragma unroll
        for (int n = 0; n < 2; ++n) {
            const int x = x0 + wn * 32 + n * 16 + l15;
            const int p = (y << 7) + x;
            #pragma unroll
            for (int r = 0; r < 4; ++r) {
                const int o = ocb + r;
                const float v = acc[m][n][r] + bpack[o];
                if (o < 72) {
                    const int i = o / 18, ch = o - i * 18;
                    offs[i * (2 * 18 * HWX) + (((b * 18) + ch) << 14) + p] = v;
                } else if (o < 81) {
                    zbuf[((b * 9 + (o - 72)) << 14) + p] = 3.f / (1.f + expf(-v));
                } else if (o < 90) {
                    mbuf[((b * 9 + (o - 81)) << 14) + p] = 1.f / (1.f + expf(-v));
                }
            }
        }
    }
}

// ---------------------------------------------------------------------------
// Transpose img fp32 -> imgT bf16 channel-last.
// ---------------------------------------------------------------------------
__global__ __launch_bounds__(256) void transpose_kernel(
    const float* __restrict__ i0, const float* __restrict__ i1,
    const float* __restrict__ i2, const float* __restrict__ i3,
    ushort* __restrict__ imgT)
{
    const int img = blockIdx.z;
    const int b   = blockIdx.y;
    const int p0  = blockIdx.x << 6;
    const float* src = (img == 0) ? i0 : (img == 1) ? i1 : (img == 2) ? i2 : i3;

    __shared__ float tile[64][65];
    const int t = threadIdx.x;
    const int pp = t & 63, c0 = t >> 6;
    #pragma unroll
    for (int k = 0; k < 16; ++k) {
        const int c = (k << 2) + c0;
        tile[c][pp] = src[(((b << 6) + c) << 14) + p0 + pp];
    }
    __syncthreads();
    const int c2 = t & 31, pl = t >> 5;
    #pragma unroll
    for (int k = 0; k < 8; ++k) {
        const int pi = (k << 3) + pl;
        const uint packed = (uint)f2bf(tile[2 * c2][pi])
                          | ((uint)f2bf(tile[2 * c2 + 1][pi]) << 16);
        *(uint*)(imgT + ((size_t)(((img << 1) + b) << 14) + p0 + pi) * 64 + 2 * c2)
            = packed;
    }
}

// ---------------------------------------------------------------------------
// Fused deform-sample + MFMA contraction — r16 WIDE-LOAD config (best: 53.5us)
// with r18 change: n-loop `#pragma unroll 2` to expose 2 independent load
// chains (16 loads in flight potential; VGPR headroom 44 -> cap ~102).
// ---------------------------------------------------------------------------
__global__ __launch_bounds__(256, 5) void fused_kernel(
    const float* __restrict__ offs,   // [4][2][18][HWX]
    const float* __restrict__ zbuf,   // [2][9][HWX]
    const float* __restrict__ mbuf,   // [2][9][HWX]
    const ushort* __restrict__ imgT,  // [4][2][HWX][64] bf16
    const __hip_bfloat16* __restrict__ WcPk,  // [64][576] n-major
    float* __restrict__ out)          // [2][64][HWX]
{
    __shared__ __hip_bfloat16 s_sb[16 * 584];   // 18688 B
    __shared__ uint4 s_tap[16 * 36];            // 9216 B  => 27904 B

    const int t   = threadIdx.x;
    const int pid = blockIdx.x;
    const int b   = pid >> 10;
    const int rem = pid & 1023;
    const int h   = rem >> 3;
    const int w0p = (rem & 7) << 4;

    // ---- phase A: taps -> packed uint4 ----
    for (int u = t; u < 576; u += 256) {
        const int px_  = u / 36;
        const int unit = u - px_ * 36;
        const int i    = unit / 9;
        const int n    = unit - i * 9;
        const int wcol = w0p + px_;
        const int p    = (h << 7) + wcol;

        const float* ob = offs + i * (2 * 18 * HWX) + ((b * 18) << 14);
        const float ox = ob[(n << 14) + p];
        const float oy = ob[((n + 9) << 14) + p];
        const float z  = zbuf[((b * 9 + n) << 14) + p];
        const float mm = mbuf[((b * 9 + n) << 14) + p];

        const float zc0 = (i == 0) ? 1.f : 0.f;
        const float zc1 = (i == 0) ? (-11.f / 6.f) : (i == 1) ? 3.f
                         : (i == 2) ? -1.5f : (1.f / 3.f);
        const float zc2 = (i == 0) ? 1.f : (i == 1) ? -2.5f
                         : (i == 2) ? 2.f : -0.5f;
        const float zc3 = (i == 0) ? (-1.f / 6.f) : (i == 1) ? 0.5f
                         : (i == 2) ? -0.5f : (1.f / 6.f);
        const float zw   = zc0 + z * (zc1 + z * (zc2 + z * zc3));
        const float coef = zw * mm;

        const float pxf = (float)(h + n / 3) + ox;
        const float pyf = (float)(wcol + n % 3) + oy;
        const float flx = floorf(pxf), fly = floorf(pyf);
        const float qltx = fminf(fmaxf(flx, 0.f), 129.f);
        const float qrbx = fminf(fmaxf(flx + 1.f, 0.f), 129.f);
        const float qlty = fminf(fmaxf(fly, 0.f), 129.f);
        const float qrby = fminf(fmaxf(fly + 1.f, 0.f), 129.f);
        const float pxc = fminf(fmaxf(pxf, 0.f), 129.f);
        const float pyc = fminf(fmaxf(pyf, 0.f), 129.f);
        const float gxl = 1.f + (qltx - pxc);
        const float gxr = 1.f - (qrbx - pxc);
        const float gyl = 1.f + (qlty - pyc);
        const float gyr = 1.f - (qrby - pyc);
        const int ixl = (int)qltx, ixr = (int)qrbx;
        const int iyl = (int)qlty, iyr = (int)qrby;

        uint i0_, i1_, i2_, i3_, u0_, u1_, u2_, u3_;
        auto mk = [&](int qx, int qy, float g, uint& ii, uint& ww) {
            const bool valid = (qx >= 1) && (qx <= 128) && (qy >= 1) && (qy <= 128);
            ii = valid ? (uint)(((qx - 1) << 7) + (qy - 1)) : 0u;
            ww = valid ? (uint)f2bf(g * coef) : 0u;
        };
        mk(ixl, iyl, gxl * gyl, i0_, u0_);
        mk(ixr, iyr, gxr * gyr, i1_, u1_);
        mk(ixr, iyl, gxr * gyl, i2_, u2_);
        mk(ixl, iyr, gxl * gyr, i3_, u3_);
        uint4 tp;
        tp.x = i0_ | (i1_ << 16);
        tp.y = i2_ | (i3_ << 16);
        tp.z = u0_ | (u1_ << 16);
        tp.w = u2_ | (u3_ << 16);
        s_tap[u] = tp;
    }
    __syncthreads();

    // ---- phase B: wide gather, 2 taps per lane-half, 2 n-chains in flight
    const int lane = t & 63;
    const int wv   = t >> 6;
    const int c8   = lane & 7;
    const int half = (lane >> 3) & 1;
    const int pxs  = lane >> 4;
    const int px   = (wv << 2) + pxs;
    const int tb   = px * 36;
    const int cByte = c8 << 4;   // 8 channels * 2B

    #pragma unroll 2
    for (int n = 0; n < 9; ++n) {
        float s8[8];
        #pragma unroll
        for (int m = 0; m < 8; ++m) s8[m] = 0.f;

        #pragma unroll
        for (int i = 0; i < 4; ++i) {
            const uint4 tp = s_tap[tb + i * 9 + n];
            const uint  pair = half ? tp.y : tp.x;   // two tap pixel idxs
            const uint  wpr  = half ? tp.w : tp.z;   // two bf16 weights
            const float wA = __uint_as_float(wpr << 16);
            const float wB = __uint_as_float(wpr & 0xffff0000u);
            const char* ibl = (const char*)imgT + (((size_t)((i << 1) + b)) << 21) + cByte;
            {
                const uint4 v = *(const uint4*)(ibl + ((pair & 0xffffu) << 7));
                s8[0] = fmaf(wA, __uint_as_float(v.x << 16),         s8[0]);
                s8[1] = fmaf(wA, __uint_as_float(v.x & 0xffff0000u), s8[1]);
                s8[2] = fmaf(wA, __uint_as_float(v.y << 16),         s8[2]);
                s8[3] = fmaf(wA, __uint_as_float(v.y & 0xffff0000u), s8[3]);
                s8[4] = fmaf(wA, __uint_as_float(v.z << 16),         s8[4]);
                s8[5] = fmaf(wA, __uint_as_float(v.z & 0xffff0000u), s8[5]);
                s8[6] = fmaf(wA, __uint_as_float(v.w << 16),         s8[6]);
                s8[7] = fmaf(wA, __uint_as_float(v.w & 0xffff0000u), s8[7]);
            }
            {
                const uint4 v = *(const uint4*)(ibl + ((pair >> 16) << 7));
                s8[0] = fmaf(wB, __uint_as_float(v.x << 16),         s8[0]);
                s8[1] = fmaf(wB, __uint_as_float(v.x & 0xffff0000u), s8[1]);
                s8[2] = fmaf(wB, __uint_as_float(v.y << 16),         s8[2]);
                s8[3] = fmaf(wB, __uint_as_float(v.y & 0xffff0000u), s8[3]);
                s8[4] = fmaf(wB, __uint_as_float(v.z << 16),         s8[4]);
                s8[5] = fmaf(wB, __uint_as_float(v.z & 0xffff0000u), s8[5]);
                s8[6] = fmaf(wB, __uint_as_float(v.w << 16),         s8[6]);
                s8[7] = fmaf(wB, __uint_as_float(v.w & 0xffff0000u), s8[7]);
            }
        }

        // combine the two tap-halves (lanes l and l^8)
        #pragma unroll
        for (int m = 0; m < 8; ++m) s8[m] += __shfl_xor(s8[m], 8);

        if (half == 0) {
            uint4 pk;
            pk.x = (uint)f2bf(s8[0]) | ((uint)f2bf(s8[1]) << 16);
            pk.y = (uint)f2bf(s8[2]) | ((uint)f2bf(s8[3]) << 16);
            pk.z = (uint)f2bf(s8[4]) | ((uint)f2bf(s8[5]) << 16);
            pk.w = (uint)f2bf(s8[6]) | ((uint)f2bf(s8[7]) << 16);
            *(uint4*)((char*)s_sb + px * 1168 + n * 128 + cByte) = pk;
        }
    }
    __syncthreads();

    // ---- phase C: MFMA contraction (K n-major), wave wv -> oc block wv*16
    const int l15  = lane & 15;
    const int kgrp = lane >> 4;
    const ushort* Wb = (const ushort*)WcPk + (wv * 16 + l15) * 576 + kgrp * 8;
    const ushort* sb = (const ushort*)s_sb + l15 * 584 + kgrp * 8;

    f32x4 acc = {0.f, 0.f, 0.f, 0.f};
    #pragma unroll
    for (int ks = 0; ks < 18; ++ks) {
        const short8v a  = *(const short8v*)(Wb + ks * 32);
        const short8v bb = *(const short8v*)(sb + ks * 32);
        acc = __builtin_amdgcn_mfma_f32_16x16x32_bf16(a, bb, acc, 0, 0, 0);
    }

    const int p = (h << 7) + w0p + l15;
    #pragma unroll
    for (int r = 0; r < 4; ++r) {
        const int oc = wv * 16 + (kgrp << 2) + r;
        out[(((b << 6) + oc) << 14) + p] = acc[r];
    }
}

// ---------------------------------------------------------------------------
extern "C" void kernel_launch(void* const* d_in, const int* in_sizes, int n_in,
                              void* d_out, int out_size, void* d_ws, size_t ws_size,
                              hipStream_t stream) {
    (void)in_sizes; (void)n_in; (void)out_size; (void)ws_size;
    const float* img1  = (const float*)d_in[0];
    const float* img2  = (const float*)d_in[1];
    const float* img4  = (const float*)d_in[2];
    const float* img5  = (const float*)d_in[3];
    const float* osrc  = (const float*)d_in[4];
    const float* w_pc1 = (const float*)d_in[5];
    const float* b_pc1 = (const float*)d_in[6];
    const float* w_pc2 = (const float*)d_in[7];
    const float* b_pc2 = (const float*)d_in[8];
    const float* w_pc4 = (const float*)d_in[9];
    const float* b_pc4 = (const float*)d_in[10];
    const float* w_pc5 = (const float*)d_in[11];
    const float* b_pc5 = (const float*)d_in[12];
    const float* w_z   = (const float*)d_in[13];
    const float* b_z   = (const float*)d_in[14];
    const float* w_m   = (const float*)d_in[15];
    const float* b_m   = (const float*)d_in[16];
    const float* w_cv  = (const float*)d_in[17];
    float* out = (float*)d_out;

    float* wsf  = (float*)d_ws;
    float* offs = wsf;                    // 4 * 589824 floats
    float* zbuf = wsf + 4 * 589824;       // 294912
    float* mbuf = zbuf + 294912;          // 294912
    float* WcTr = mbuf + 294912;          // 36864-float region
    float* imgTr = WcTr + 36864;          // 8388608-float region

    __hip_bfloat16* WcPk  = (__hip_bfloat16*)WcTr;
    ushort*         imgTb = (ushort*)imgTr;

    // Wpk/bpack/osT ALIAS the imgT region (conv pipeline finishes before
    // transpose_kernel overwrites imgT — same-stream serialization).
    __hip_bfloat16* Wpk   = (__hip_bfloat16*)imgTr;            // 153600 bf16
    float*          bpack = imgTr + 76800;                     // 96 f32
    __hip_bfloat16* osT   = (__hip_bfloat16*)(imgTr + 76912);  // 2230272 bf16

    prep_kernel<<<dim3(1008), 256, 0, stream>>>(
        w_pc1, b_pc1, w_pc2, b_pc2, w_pc4, b_pc4, w_pc5, b_pc5,
        w_z, b_z, w_m, b_m, osrc, w_cv, Wpk, bpack, osT, WcPk);
    conv_mfma_kernel<<<dim3(256, 2), 256, 0, stream>>>(
        Wpk, bpack, osT, offs, zbuf, mbuf);
    transpose_kernel<<<dim3(256, 2, 4), 256, 0, stream>>>(img1, img2, img4, img5, imgTb);
    fused_kernel<<<dim3(2048), 256, 0, stream>>>(offs, zbuf, mbuf, imgTb, WcPk, out);
}

// Round 20
// 96.766 us; speedup vs baseline: 1.1441x; 1.0174x over previous
//
#include <hip/hip_runtime.h>
#include <hip/hip_bf16.h>
#include <math.h>

#define HWX 16384   // 128*128 pixels per (b, channel) plane

typedef __attribute__((ext_vector_type(8))) short short8v;
typedef __attribute__((ext_vector_type(4))) float f32x4;

__device__ inline ushort f2bf(float x) {
    union { __hip_bfloat16 h; ushort u; } cv;
    cv.h = __float2bfloat16(x);
    return cv.u;
}

// ---------------------------------------------------------------------------
// Combined prep: [0,600) packw | [600,864) packosT | [864,1008) wcpk
// ---------------------------------------------------------------------------
__global__ __launch_bounds__(256) void prep_kernel(
    const float* __restrict__ w1, const float* __restrict__ b1,
    const float* __restrict__ w2, const float* __restrict__ b2,
    const float* __restrict__ w4, const float* __restrict__ b4,
    const float* __restrict__ w5, const float* __restrict__ b5,
    const float* __restrict__ wz, const float* __restrict__ bz,
    const float* __restrict__ wm, const float* __restrict__ bm,
    const float* __restrict__ osrc, const float* __restrict__ wc,
    __hip_bfloat16* __restrict__ Wpk, float* __restrict__ bpack,
    __hip_bfloat16* __restrict__ osT, __hip_bfloat16* __restrict__ WcPk)
{
    const int bid = blockIdx.x;
    if (bid < 600) {
        const int idx = bid * 256 + threadIdx.x;
        if (idx < 96) {
            const int o = idx; float v = 0.f;
            if      (o < 18) v = b1[o];
            else if (o < 36) v = b2[o - 18];
            else if (o < 54) v = b4[o - 36];
            else if (o < 72) v = b5[o - 54];
            else if (o < 81) v = bz[o - 72];
            else if (o < 90) v = bm[o - 81];
            bpack[o] = v;
        }
        if (idx < 96 * 1600) {
            const int o   = idx / 1600;
            const int k   = idx - o * 1600;
            const int kyx = k >> 6;
            const int ic  = k & 63;
            const int off = ic * 25 + kyx;
            float v = 0.f;
            if      (o < 18) v = w1[o * 1600 + off];
            else if (o < 36) v = w2[(o - 18) * 1600 + off];
            else if (o < 54) v = w4[(o - 36) * 1600 + off];
            else if (o < 72) v = w5[(o - 54) * 1600 + off];
            else if (o < 81) v = wz[(o - 72) * 1600 + off];
            else if (o < 90) v = wm[(o - 81) * 1600 + off];
            Wpk[idx] = __float2bfloat16(v);
        }
    } else if (bid < 864) {
        const int blk = bid - 600;
        const int yy = blk % 132;
        const int b  = blk / 132;
        __hip_bfloat16* dst = osT + ((size_t)b * 132 + yy) * 132 * 64;
        for (int idx = threadIdx.x; idx < 132 * 64; idx += 256) {
            const int xx = idx >> 6;
            const int c  = idx & 63;
            float v = 0.f;
            if (yy >= 2 && yy < 130 && xx >= 2 && xx < 130)
                v = osrc[(((b << 6) + c) << 14) + ((yy - 2) << 7) + (xx - 2)];
            dst[idx] = __float2bfloat16(v);
        }
    } else {
        const int idx = (bid - 864) * 256 + threadIdx.x;
        if (idx < 36864) {
            const int oc  = idx / 576;
            const int cnp = idx - oc * 576;
            const int n   = cnp >> 6;
            const int c   = cnp & 63;
            WcPk[idx] = __float2bfloat16(wc[oc * 576 + c * 9 + n]);
        }
    }
}

// ---------------------------------------------------------------------------
// MFMA conv, 2-phase LDS-staged GEMM (validated r11).
// ---------------------------------------------------------------------------
__global__ __launch_bounds__(256) void conv_mfma_kernel(
    const __hip_bfloat16* __restrict__ Wpk,
    const float* __restrict__ bpack,
    const __hip_bfloat16* __restrict__ osT,
    float* __restrict__ offs, float* __restrict__ zbuf, float* __restrict__ mbuf)
{
    __shared__ __align__(16) ushort slab[5 * 68 * 64];
    __shared__ __align__(16) ushort wbuf[2][96 * 64];

    const int bx = blockIdx.x;
    const int y  = bx >> 1;
    const int x0 = (bx & 1) << 6;
    const int b  = blockIdx.y;
    const int t    = threadIdx.x;
    const int wv   = t >> 6;
    const int lane = t & 63;
    const int l15  = lane & 15;
    const int kgrp = lane >> 4;
    const int wm   = wv >> 1;
    const int wn   = wv & 1;

    const ushort* ob = (const ushort*)osT + (size_t)b * (132 * 132 * 64);
    const ushort* Wg = (const ushort*)Wpk;

    for (int c = t; c < 2720; c += 256) {
        const int r5  = c / 544;
        const int rem = c - r5 * 544;
        const int col = rem >> 3;
        const int cb  = rem & 7;
        const short8v v = *(const short8v*)(ob + (((y + r5) * 132 + x0 + col) << 6) + (cb << 3));
        const int slot = r5 * 544 + (col << 3) + (cb ^ (col & 7));
        *(short8v*)((char*)slab + slot * 16) = v;
    }

#define STAGE_W(kyx, bi)                                                       \
    _Pragma("unroll")                                                          \
    for (int it = 0; it < 3; ++it) {                                           \
        const int c  = it * 256 + t;                                           \
        const int oc = c >> 3, cb = c & 7;                                     \
        const ushort* src = Wg + oc * 1600 + (kyx) * 64 + ((cb ^ (oc & 7)) << 3); \
        __builtin_amdgcn_global_load_lds(                                      \
            (const __attribute__((address_space(1))) void*)src,                \
            (__attribute__((address_space(3))) void*)((char*)wbuf[bi] + (it * 256 + wv * 64) * 16), \
            16, 0, 0);                                                         \
    }

    STAGE_W(0, 0)
    __syncthreads();

    f32x4 acc[3][2];
    #pragma unroll
    for (int m = 0; m < 3; ++m)
        #pragma unroll
        for (int n = 0; n < 2; ++n) acc[m][n] = (f32x4){0.f, 0.f, 0.f, 0.f};

    for (int kyx = 0; kyx < 25; ++kyx) {
        const int bi = kyx & 1;
        if (kyx < 24) STAGE_W(kyx + 1, bi ^ 1)
        const int ky = kyx / 5, kx = kyx % 5;
        #pragma unroll
        for (int kc = 0; kc < 2; ++kc) {
            const int kcg = (kc << 2) + kgrp;
            short8v af[3], bf[2];
            #pragma unroll
            for (int m = 0; m < 3; ++m) {
                const int oc = wm * 48 + m * 16 + l15;
                af[m] = *(const short8v*)((char*)wbuf[bi] + ((oc << 3) + (kcg ^ (oc & 7))) * 16);
            }
            #pragma unroll
            for (int n = 0; n < 2; ++n) {
                const int col = wn * 32 + n * 16 + l15 + kx;
                bf[n] = *(const short8v*)((char*)slab + ((ky * 68 + col) * 8 + (kcg ^ (col & 7))) * 16);
            }
            #pragma unroll
            for (int m = 0; m < 3; ++m)
                #pragma unroll
                for (int n = 0; n < 2; ++n)
                    acc[m][n] = __builtin_amdgcn_mfma_f32_16x16x32_bf16(af[m], bf[n], acc[m][n], 0, 0, 0);
        }
        __syncthreads();
    }
#undef STAGE_W

    #pragma unroll
    for (int m = 0; m < 3; ++m) {
        const int ocb = wm * 48 + m * 16 + (kgrp << 2);
        #pragma unroll
        for (int n = 0; n < 2; ++n) {
            const int x = x0 + wn * 32 + n * 16 + l15;
            const int p = (y << 7) + x;
            #pragma unroll
            for (int r = 0; r < 4; ++r) {
                const int o = ocb + r;
                const float v = acc[m][n][r] + bpack[o];
                if (o < 72) {
                    const int i = o / 18, ch = o - i * 18;
                    offs[i * (2 * 18 * HWX) + (((b * 18) + ch) << 14) + p] = v;
                } else if (o < 81) {
                    zbuf[((b * 9 + (o - 72)) << 14) + p] = 3.f / (1.f + expf(-v));
                } else if (o < 90) {
                    mbuf[((b * 9 + (o - 81)) << 14) + p] = 1.f / (1.f + expf(-v));
                }
            }
        }
    }
}

// ---------------------------------------------------------------------------
// Transpose img fp32 -> imgT bf16 channel-last.
// ---------------------------------------------------------------------------
__global__ __launch_bounds__(256) void transpose_kernel(
    const float* __restrict__ i0, const float* __restrict__ i1,
    const float* __restrict__ i2, const float* __restrict__ i3,
    ushort* __restrict__ imgT)
{
    const int img = blockIdx.z;
    const int b   = blockIdx.y;
    const int p0  = blockIdx.x << 6;
    const float* src = (img == 0) ? i0 : (img == 1) ? i1 : (img == 2) ? i2 : i3;

    __shared__ float tile[64][65];
    const int t = threadIdx.x;
    const int pp = t & 63, c0 = t >> 6;
    #pragma unroll
    for (int k = 0; k < 16; ++k) {
        const int c = (k << 2) + c0;
        tile[c][pp] = src[(((b << 6) + c) << 14) + p0 + pp];
    }
    __syncthreads();
    const int c2 = t & 31, pl = t >> 5;
    #pragma unroll
    for (int k = 0; k < 8; ++k) {
        const int pi = (k << 3) + pl;
        const uint packed = (uint)f2bf(tile[2 * c2][pi])
                          | ((uint)f2bf(tile[2 * c2 + 1][pi]) << 16);
        *(uint*)(imgT + ((size_t)(((img << 1) + b) << 14) + p0 + pi) * 64 + 2 * c2)
            = packed;
    }
}

// ---------------------------------------------------------------------------
// Fused deform-sample + MFMA contraction — r20: ASM-PIPELINED gather
// (r19 intent, macro-hygiene fixed: FMA8 params renamed so `.w` member
// access is not captured).
// ---------------------------------------------------------------------------
#define UAF __uint_as_float

__global__ __launch_bounds__(256, 4) void fused_kernel(
    const float* __restrict__ offs,   // [4][2][18][HWX]
    const float* __restrict__ zbuf,   // [2][9][HWX]
    const float* __restrict__ mbuf,   // [2][9][HWX]
    const ushort* __restrict__ imgT,  // [4][2][HWX][64] bf16
    const __hip_bfloat16* __restrict__ WcPk,  // [64][576] n-major
    float* __restrict__ out)          // [2][64][HWX]
{
    __shared__ __hip_bfloat16 s_sb[16 * 584];   // 18688 B
    __shared__ uint4 s_tap[16 * 36];            // 9216 B  => 27904 B

    const int t   = threadIdx.x;
    const int pid = blockIdx.x;
    const int b   = pid >> 10;
    const int rem = pid & 1023;
    const int h   = rem >> 3;
    const int w0p = (rem & 7) << 4;

    // ---- phase A: taps -> packed uint4 ----
    for (int u = t; u < 576; u += 256) {
        const int px_  = u / 36;
        const int unit = u - px_ * 36;
        const int i    = unit / 9;
        const int n    = unit - i * 9;
        const int wcol = w0p + px_;
        const int p    = (h << 7) + wcol;

        const float* ob = offs + i * (2 * 18 * HWX) + ((b * 18) << 14);
        const float ox = ob[(n << 14) + p];
        const float oy = ob[((n + 9) << 14) + p];
        const float z  = zbuf[((b * 9 + n) << 14) + p];
        const float mm = mbuf[((b * 9 + n) << 14) + p];

        const float zc0 = (i == 0) ? 1.f : 0.f;
        const float zc1 = (i == 0) ? (-11.f / 6.f) : (i == 1) ? 3.f
                         : (i == 2) ? -1.5f : (1.f / 3.f);
        const float zc2 = (i == 0) ? 1.f : (i == 1) ? -2.5f
                         : (i == 2) ? 2.f : -0.5f;
        const float zc3 = (i == 0) ? (-1.f / 6.f) : (i == 1) ? 0.5f
                         : (i == 2) ? -0.5f : (1.f / 6.f);
        const float zw   = zc0 + z * (zc1 + z * (zc2 + z * zc3));
        const float coef = zw * mm;

        const float pxf = (float)(h + n / 3) + ox;
        const float pyf = (float)(wcol + n % 3) + oy;
        const float flx = floorf(pxf), fly = floorf(pyf);
        const float qltx = fminf(fmaxf(flx, 0.f), 129.f);
        const float qrbx = fminf(fmaxf(flx + 1.f, 0.f), 129.f);
        const float qlty = fminf(fmaxf(fly, 0.f), 129.f);
        const float qrby = fminf(fmaxf(fly + 1.f, 0.f), 129.f);
        const float pxc = fminf(fmaxf(pxf, 0.f), 129.f);
        const float pyc = fminf(fmaxf(pyf, 0.f), 129.f);
        const float gxl = 1.f + (qltx - pxc);
        const float gxr = 1.f - (qrbx - pxc);
        const float gyl = 1.f + (qlty - pyc);
        const float gyr = 1.f - (qrby - pyc);
        const int ixl = (int)qltx, ixr = (int)qrbx;
        const int iyl = (int)qlty, iyr = (int)qrby;

        uint i0_, i1_, i2_, i3_, u0_, u1_, u2_, u3_;
        auto mk = [&](int qx, int qy, float g, uint& ii, uint& ww) {
            const bool valid = (qx >= 1) && (qx <= 128) && (qy >= 1) && (qy <= 128);
            ii = valid ? (uint)(((qx - 1) << 7) + (qy - 1)) : 0u;
            ww = valid ? (uint)f2bf(g * coef) : 0u;
        };
        mk(ixl, iyl, gxl * gyl, i0_, u0_);
        mk(ixr, iyr, gxr * gyr, i1_, u1_);
        mk(ixr, iyl, gxr * gyl, i2_, u2_);
        mk(ixl, iyr, gxl * gyr, i3_, u3_);
        uint4 tp;
        tp.x = i0_ | (i1_ << 16);
        tp.y = i2_ | (i3_ << 16);
        tp.z = u0_ | (u1_ << 16);
        tp.w = u2_ | (u3_ << 16);
        s_tap[u] = tp;
    }
    __syncthreads();

    // ---- phase B: asm-pipelined wide gather ----
    const int lane = t & 63;
    const int wv   = t >> 6;
    const int c8   = lane & 7;
    const int half = (lane >> 3) & 1;
    const int pxs  = lane >> 4;
    const int px   = (wv << 2) + pxs;
    const int tb   = px * 36;
    const int cByte = c8 << 4;   // 8 channels * 2B

    const char* ibl0 = (const char*)imgT + (((size_t)(0 + b)) << 21) + cByte;
    const char* ibl1 = (const char*)imgT + (((size_t)(2 + b)) << 21) + cByte;
    const char* ibl2 = (const char*)imgT + (((size_t)(4 + b)) << 21) + cByte;
    const char* ibl3 = (const char*)imgT + (((size_t)(6 + b)) << 21) + cByte;

#define AI(n, V)                                                               \
    uint4 V##r0, V##r1, V##r2, V##r3, V##r4, V##r5, V##r6, V##r7;              \
    float V##w0, V##w1, V##w2, V##w3, V##w4, V##w5, V##w6, V##w7;              \
    {                                                                          \
        const uint4 t0 = s_tap[tb + 0 * 9 + (n)];                              \
        const uint4 t1 = s_tap[tb + 1 * 9 + (n)];                              \
        const uint4 t2 = s_tap[tb + 2 * 9 + (n)];                              \
        const uint4 t3 = s_tap[tb + 3 * 9 + (n)];                              \
        const uint p0 = half ? t0.y : t0.x, q0 = half ? t0.w : t0.z;           \
        const uint p1 = half ? t1.y : t1.x, q1 = half ? t1.w : t1.z;           \
        const uint p2 = half ? t2.y : t2.x, q2 = half ? t2.w : t2.z;           \
        const uint p3 = half ? t3.y : t3.x, q3 = half ? t3.w : t3.z;           \
        V##w0 = UAF(q0 << 16); V##w1 = UAF(q0 & 0xffff0000u);                  \
        V##w2 = UAF(q1 << 16); V##w3 = UAF(q1 & 0xffff0000u);                  \
        V##w4 = UAF(q2 << 16); V##w5 = UAF(q2 & 0xffff0000u);                  \
        V##w6 = UAF(q3 << 16); V##w7 = UAF(q3 & 0xffff0000u);                  \
        const char* a0 = ibl0 + ((p0 & 0xffffu) << 7);                         \
        const char* a1 = ibl0 + ((p0 >> 16) << 7);                             \
        const char* a2 = ibl1 + ((p1 & 0xffffu) << 7);                         \
        const char* a3 = ibl1 + ((p1 >> 16) << 7);                             \
        const char* a4 = ibl2 + ((p2 & 0xffffu) << 7);                         \
        const char* a5 = ibl2 + ((p2 >> 16) << 7);                             \
        const char* a6 = ibl3 + ((p3 & 0xffffu) << 7);                         \
        const char* a7 = ibl3 + ((p3 >> 16) << 7);                             \
        asm volatile(                                                          \
            "global_load_dwordx4 %0, %8, off\n\t"                              \
            "global_load_dwordx4 %1, %9, off\n\t"                              \
            "global_load_dwordx4 %2, %10, off\n\t"                             \
            "global_load_dwordx4 %3, %11, off\n\t"                             \
            "global_load_dwordx4 %4, %12, off\n\t"                             \
            "global_load_dwordx4 %5, %13, off\n\t"                             \
            "global_load_dwordx4 %6, %14, off\n\t"                             \
            "global_load_dwordx4 %7, %15, off"                                 \
            : "=&v"(V##r0), "=&v"(V##r1), "=&v"(V##r2), "=&v"(V##r3),          \
              "=&v"(V##r4), "=&v"(V##r5), "=&v"(V##r6), "=&v"(V##r7)           \
            : "v"(a0), "v"(a1), "v"(a2), "v"(a3),                              \
              "v"(a4), "v"(a5), "v"(a6), "v"(a7));                             \
    }

#define FMA8(Wf, Vr)                                                           \
    s8[0] = fmaf(Wf, UAF((Vr).x << 16),         s8[0]);                        \
    s8[1] = fmaf(Wf, UAF((Vr).x & 0xffff0000u), s8[1]);                        \
    s8[2] = fmaf(Wf, UAF((Vr).y << 16),         s8[2]);                        \
    s8[3] = fmaf(Wf, UAF((Vr).y & 0xffff0000u), s8[3]);                        \
    s8[4] = fmaf(Wf, UAF((Vr).z << 16),         s8[4]);                        \
    s8[5] = fmaf(Wf, UAF((Vr).z & 0xffff0000u), s8[5]);                        \
    s8[6] = fmaf(Wf, UAF((Vr).w << 16),         s8[6]);                        \
    s8[7] = fmaf(Wf, UAF((Vr).w & 0xffff0000u), s8[7]);

#define PROC(n, V)                                                             \
    {                                                                          \
        float s8[8];                                                           \
        _Pragma("unroll") for (int m = 0; m < 8; ++m) s8[m] = 0.f;             \
        FMA8(V##w0, V##r0) FMA8(V##w1, V##r1) FMA8(V##w2, V##r2)               \
        FMA8(V##w3, V##r3) FMA8(V##w4, V##r4) FMA8(V##w5, V##r5)               \
        FMA8(V##w6, V##r6) FMA8(V##w7, V##r7)                                  \
        _Pragma("unroll") for (int m = 0; m < 8; ++m)                          \
            s8[m] += __shfl_xor(s8[m], 8);                                     \
        if (half == 0) {                                                       \
            uint4 pk;                                                          \
            pk.x = (uint)f2bf(s8[0]) | ((uint)f2bf(s8[1]) << 16);              \
            pk.y = (uint)f2bf(s8[2]) | ((uint)f2bf(s8[3]) << 16);              \
            pk.z = (uint)f2bf(s8[4]) | ((uint)f2bf(s8[5]) << 16);              \
            pk.w = (uint)f2bf(s8[6]) | ((uint)f2bf(s8[7]) << 16);              \
            *(uint4*)((char*)s_sb + px * 1168 + (n) * 128 + cByte) = pk;       \
        }                                                                      \
    }

#define WAITSB(N)                                                              \
    asm volatile("s_waitcnt vmcnt(" #N ")" ::: "memory");                      \
    __builtin_amdgcn_sched_barrier(0);

    AI(0, g0)
    AI(1, g1)
    WAITSB(8)  PROC(0, g0)
    AI(2, g2)
    WAITSB(8)  PROC(1, g1)
    AI(3, g3)
    WAITSB(8)  PROC(2, g2)
    AI(4, g4)
    WAITSB(8)  PROC(3, g3)
    AI(5, g5)
    WAITSB(8)  PROC(4, g4)
    AI(6, g6)
    WAITSB(8)  PROC(5, g5)
    AI(7, g7)
    WAITSB(8)  PROC(6, g6)
    AI(8, g8)
    WAITSB(8)  PROC(7, g7)
    WAITSB(0)  PROC(8, g8)

#undef AI
#undef FMA8
#undef PROC
#undef WAITSB
    __syncthreads();

    // ---- phase C: MFMA contraction (K n-major), wave wv -> oc block wv*16
    const int l15  = lane & 15;
    const int kgrp = lane >> 4;
    const ushort* Wb = (const ushort*)WcPk + (wv * 16 + l15) * 576 + kgrp * 8;
    const ushort* sb = (const ushort*)s_sb + l15 * 584 + kgrp * 8;

    f32x4 acc = {0.f, 0.f, 0.f, 0.f};
    #pragma unroll
    for (int ks = 0; ks < 18; ++ks) {
        const short8v a  = *(const short8v*)(Wb + ks * 32);
        const short8v bb = *(const short8v*)(sb + ks * 32);
        acc = __builtin_amdgcn_mfma_f32_16x16x32_bf16(a, bb, acc, 0, 0, 0);
    }

    const int p = (h << 7) + w0p + l15;
    #pragma unroll
    for (int r = 0; r < 4; ++r) {
        const int oc = wv * 16 + (kgrp << 2) + r;
        out[(((b << 6) + oc) << 14) + p] = acc[r];
    }
}

// ---------------------------------------------------------------------------
extern "C" void kernel_launch(void* const* d_in, const int* in_sizes, int n_in,
                              void* d_out, int out_size, void* d_ws, size_t ws_size,
                              hipStream_t stream) {
    (void)in_sizes; (void)n_in; (void)out_size; (void)ws_size;
    const float* img1  = (const float*)d_in[0];
    const float* img2  = (const float*)d_in[1];
    const float* img4  = (const float*)d_in[2];
    const float* img5  = (const float*)d_in[3];
    const float* osrc  = (const float*)d_in[4];
    const float* w_pc1 = (const float*)d_in[5];
    const float* b_pc1 = (const float*)d_in[6];
    const float* w_pc2 = (const float*)d_in[7];
    const float* b_pc2 = (const float*)d_in[8];
    const float* w_pc4 = (const float*)d_in[9];
    const float* b_pc4 = (const float*)d_in[10];
    const float* w_pc5 = (const float*)d_in[11];
    const float* b_pc5 = (const float*)d_in[12];
    const float* w_z   = (const float*)d_in[13];
    const float* b_z   = (const float*)d_in[14];
    const float* w_m   = (const float*)d_in[15];
    const float* b_m   = (const float*)d_in[16];
    const float* w_cv  = (const float*)d_in[17];
    float* out = (float*)d_out;

    float* wsf  = (float*)d_ws;
    float* offs = wsf;                    // 4 * 589824 floats
    float* zbuf = wsf + 4 * 589824;       // 294912
    float* mbuf = zbuf + 294912;          // 294912
    float* WcTr = mbuf + 294912;          // 36864-float region
    float* imgTr = WcTr + 36864;          // 8388608-float region

    __hip_bfloat16* WcPk  = (__hip_bfloat16*)WcTr;
    ushort*         imgTb = (ushort*)imgTr;

    // Wpk/bpack/osT ALIAS the imgT region (conv pipeline finishes before
    // transpose_kernel overwrites imgT — same-stream serialization).
    __hip_bfloat16* Wpk   = (__hip_bfloat16*)imgTr;            // 153600 bf16
    float*          bpack = imgTr + 76800;                     // 96 f32
    __hip_bfloat16* osT   = (__hip_bfloat16*)(imgTr + 76912);  // 2230272 bf16

    prep_kernel<<<dim3(1008), 256, 0, stream>>>(
        w_pc1, b_pc1, w_pc2, b_pc2, w_pc4, b_pc4, w_pc5, b_pc5,
        w_z, b_z, w_m, b_m, osrc, w_cv, Wpk, bpack, osT, WcPk);
    conv_mfma_kernel<<<dim3(256, 2), 256, 0, stream>>>(
        Wpk, bpack, osT, offs, zbuf, mbuf);
    transpose_kernel<<<dim3(256, 2, 4), 256, 0, stream>>>(img1, img2, img4, img5, imgTb);
    fused_kernel<<<dim3(2048), 256, 0, stream>>>(offs, zbuf, mbuf, imgTb, WcPk, out);
}